// Round 1
// baseline (157.410 us; speedup 1.0000x reference)
//
#include <hip/hip_runtime.h>

#define BB 128
#define TT 4096
#define LL 43
#define CC 46          // L + 3
#define CHUNK 256
#define NC (TT / CHUNK)   // 16 chunks
#define TPB 256
#define NEGF (-1e30f)
#define L2E 1.44269504088896340736f
#define LN2 0.69314718055994530942f

// logaddexp in log2 domain
__device__ __forceinline__ float la2(float x, float y) {
    float mx = fmaxf(x, y), mn = fminf(x, y);
    return mx + log2f(1.0f + exp2f(mn - mx));
}

// ws const layout (floats):
// [0..42]  p0[j] = exp(g0[1+j])        (softmax probs, label transitions from state0)
// [43..85] p1[j] = exp(g1[1+j])        (label transitions from state1)
// [86]     pO    = exp(g0[0])
// [87]     s0I2  = g0[L+1] * log2(e)
// [88]     s1I2  = g1[0]   * log2(e)
// [89]     sfin2 = g0[L+2] * log2(e)
__global__ void crf_prep(const float* __restrict__ dp, float* __restrict__ cst) {
    int lane = threadIdx.x; // 64 threads, 1 wave
    float x0 = (lane < CC) ? dp[lane] : NEGF;
    float x1 = (lane < LL + 1) ? dp[CC + lane] : NEGF;
    float mx0 = x0, mx1 = x1;
    #pragma unroll
    for (int m = 1; m < 64; m <<= 1) {
        mx0 = fmaxf(mx0, __shfl_xor(mx0, m));
        mx1 = fmaxf(mx1, __shfl_xor(mx1, m));
    }
    float e0 = (lane < CC) ? expf(x0 - mx0) : 0.0f;
    float e1 = (lane < LL + 1) ? expf(x1 - mx1) : 0.0f;
    float s0 = e0, s1 = e1;
    #pragma unroll
    for (int m = 1; m < 64; m <<= 1) {
        s0 += __shfl_xor(s0, m);
        s1 += __shfl_xor(s1, m);
    }
    float g0 = x0 - mx0 - logf(s0);   // log-softmax (natural log) of group0, this lane
    float g1 = x1 - mx1 - logf(s1);   // group1
    if (lane >= 1 && lane <= LL) {
        cst[lane - 1] = expf(g0);        // p0[j], j = lane-1
        cst[LL + lane - 1] = expf(g1);   // p1[j]
    }
    if (lane == 0) { cst[86] = expf(g0); cst[88] = g1 * L2E; }
    if (lane == LL + 1) cst[87] = g0 * L2E;  // s_0I
    if (lane == LL + 2) cst[89] = g0 * L2E;  // s_fin
}

__global__ __launch_bounds__(TPB) void crf_chunk(
    const float* __restrict__ lp, const int* __restrict__ lens,
    const int* __restrict__ labels, const float* __restrict__ cst,
    float* __restrict__ res) {
    int b = blockIdx.y, c = blockIdx.x;
    int t0 = c * CHUNK;
    int len = lens[b];
    float* r = res + (b * NC + c) * 8;
    if (t0 >= len) {  // fully masked chunk: identity matrix, zero numerator; skip HBM
        if (threadIdx.x == 0) { r[0] = 0.f; r[1] = NEGF; r[2] = NEGF; r[3] = 0.f; r[4] = 0.f; }
        return;
    }
    __shared__ float tile[CHUNK * CC];   // 47104 B; lane stride 46 floats -> 2-way bank alias (free)
    __shared__ float wres[TPB / 64][5];
    // coalesced float4 staging: base (b*T + t0)*46*4 bytes is 16B-aligned (t0 % 256 == 0)
    const float4* src = (const float4*)(lp + (size_t)(b * TT + t0) * CC);
    float4* dst = (float4*)tile;
    #pragma unroll 4
    for (int i = threadIdx.x; i < CHUNK * CC / 4; i += TPB) dst[i] = src[i];
    __syncthreads();

    int tid = threadIdx.x;
    int t = t0 + tid;
    const float* vr = tile + tid * CC;
    float m00, m01, m10, m11, tok;
    {
        float w1 = exp2f(L2E * vr[1]);       // P(col 1)
        float v2s = L2E * vr[2];
        float dot0 = cst[2 * LL] * w1;       // pO * P(col1)
        float dot1 = 0.f;
        #pragma unroll
        for (int j = 0; j < LL; ++j) {
            float w = exp2f(L2E * vr[3 + j]);   // P(label col), shared by both dots
            dot0 = fmaf(cst[j], w, dot0);
            dot1 = fmaf(cst[LL + j], w, dot1);
        }
        m00 = log2f(dot0);
        m01 = log2f(dot1);
        m10 = cst[87] + v2s;
        m11 = cst[88] + v2s;
        int lab = labels[b * TT + t];        // in [1, C)
        tok = vr[lab];                       // raw (natural-log) value for numerator
    }
    if (t >= len) { m00 = 0.f; m01 = NEGF; m10 = NEGF; m11 = 0.f; tok = 0.f; }

    // order-preserving xor-tree composition across the wave (64 consecutive timesteps)
    int lane = tid & 63;
    #pragma unroll
    for (int m = 1; m < 64; m <<= 1) {
        float p00 = __shfl_xor(m00, m), p01 = __shfl_xor(m01, m);
        float p10 = __shfl_xor(m10, m), p11 = __shfl_xor(m11, m);
        bool up = (lane & m) != 0;   // my segment is LATER in time
        float a00 = up ? m00 : p00, a01 = up ? m01 : p01;   // A = later
        float a10 = up ? m10 : p10, a11 = up ? m11 : p11;
        float b00 = up ? p00 : m00, b01 = up ? p01 : m01;   // B = earlier
        float b10 = up ? p10 : m10, b11 = up ? p11 : m11;
        m00 = la2(a00 + b00, a01 + b10);
        m01 = la2(a00 + b01, a01 + b11);
        m10 = la2(a10 + b00, a11 + b10);
        m11 = la2(a10 + b01, a11 + b11);
        tok += __shfl_xor(tok, m);
    }
    if (lane == 0) {
        int w = tid >> 6;
        wres[w][0] = m00; wres[w][1] = m01; wres[w][2] = m10; wres[w][3] = m11; wres[w][4] = tok;
    }
    __syncthreads();
    if (tid == 0) {
        float c00 = wres[0][0], c01 = wres[0][1], c10 = wres[0][2], c11 = wres[0][3];
        float num = wres[0][4];
        #pragma unroll
        for (int w = 1; w < TPB / 64; ++w) {   // ascending time: new = M_w (later) o C (earlier)
            float a00 = wres[w][0], a01 = wres[w][1], a10 = wres[w][2], a11 = wres[w][3];
            float n00 = la2(a00 + c00, a01 + c10);
            float n01 = la2(a00 + c01, a01 + c11);
            float n10 = la2(a10 + c00, a11 + c10);
            float n11 = la2(a10 + c01, a11 + c11);
            c00 = n00; c01 = n01; c10 = n10; c11 = n11;
            num += wres[w][4];
        }
        r[0] = c00; r[1] = c01; r[2] = c10; r[3] = c11; r[4] = num;
    }
}

__global__ void crf_final(const float* __restrict__ cst, const float* __restrict__ res,
                          float* __restrict__ out) {
    int b = threadIdx.x;   // 128 threads, one per batch element
    float a0 = 0.f, a1 = NEGF, num = 0.f;
    #pragma unroll
    for (int c = 0; c < NC; ++c) {
        const float* r = res + (b * NC + c) * 8;
        float n0 = la2(r[0] + a0, r[1] + a1);
        float n1 = la2(r[2] + a0, r[3] + a1);
        a0 = n0; a1 = n1; num += r[4];
    }
    float den = (a0 + cst[89]) * LN2;   // log2 -> natural log
    float val = num - den;
    #pragma unroll
    for (int m = 1; m < 64; m <<= 1) val += __shfl_xor(val, m);
    __shared__ float part[2];
    if ((b & 63) == 0) part[b >> 6] = val;
    __syncthreads();
    if (b == 0) out[0] = part[0] + part[1];
}

extern "C" void kernel_launch(void* const* d_in, const int* in_sizes, int n_in,
                              void* d_out, int out_size, void* d_ws, size_t ws_size,
                              hipStream_t stream) {
    const float* lp = (const float*)d_in[0];      // (B,T,C) f32
    const float* dp = (const float*)d_in[1];      // (2L+4,) f32
    const int* lens = (const int*)d_in[2];        // (B,) i32
    const int* labels = (const int*)d_in[3];      // (B,T) i32
    float* out = (float*)d_out;
    float* cst = (float*)d_ws;                    // 90 consts (padded to 96)
    float* res = cst + 96;                        // B*NC*8 floats = 64 KB

    hipLaunchKernelGGL(crf_prep, dim3(1), dim3(64), 0, stream, dp, cst);
    hipLaunchKernelGGL(crf_chunk, dim3(NC, BB), dim3(TPB), 0, stream, lp, lens, labels, cst, res);
    hipLaunchKernelGGL(crf_final, dim3(1), dim3(128), 0, stream, cst, res, out);
}